// Round 1
// baseline (218.374 us; speedup 1.0000x reference)
//
#include <hip/hip_runtime.h>
#include <hip/hip_bf16.h>
#include <stdint.h>

#define B_SZ 4096
#define D_K  2048   // D_IN + D_H
#define DH   1024

#define BM 128      // M rows per block
#define BN_H 32     // h columns per block (x4 gates = 128 N columns)
#define BK 32       // K elements per LDS tile

typedef __attribute__((ext_vector_type(8))) short short8;
typedef __attribute__((ext_vector_type(4))) float floatx4;

__device__ __forceinline__ float fast_sigmoid(float x) {
  return 1.0f / (1.0f + __expf(-x));
}
__device__ __forceinline__ float fast_tanh(float x) {
  return 2.0f / (1.0f + __expf(-2.0f * x)) - 1.0f;
}

// Cast fp32 inputs to bf16 workspace:
//  Abf[m][k] = (k<1024 ? x[m][k] : h_prev[m][k-1024])          [4096][2048]
//  Wbf[g*1024+h][k] = W_g[h][k]   (gate-major concat)          [4096][2048]
__global__ __launch_bounds__(256) void prep_kernel(
    const float* __restrict__ xin, const float* __restrict__ hprev,
    const float* __restrict__ Wi, const float* __restrict__ Wf,
    const float* __restrict__ Wc, const float* __restrict__ Wo,
    __hip_bfloat16* __restrict__ Abf, __hip_bfloat16* __restrict__ Wbf)
{
  const int NT = (B_SZ * D_K) / 8;  // threads per matrix (8 elems/thread)
  int t = blockIdx.x * blockDim.x + threadIdx.x;
  const float* src;
  __hip_bfloat16* dst;
  if (t < NT) {
    int idx8 = t * 8;
    int m = idx8 >> 11;
    int k = idx8 & (D_K - 1);
    src = (k < 1024) ? (xin + m * 1024 + k) : (hprev + m * 1024 + (k - 1024));
    dst = Abf + idx8;
  } else {
    t -= NT;
    int idx8 = t * 8;
    int n = idx8 >> 11;
    int k = idx8 & (D_K - 1);
    int g = n >> 10, h = n & 1023;
    const float* wsrc = (g == 0) ? Wi : (g == 1) ? Wf : (g == 2) ? Wc : Wo;
    src = wsrc + (size_t)h * D_K + k;
    dst = Wbf + idx8;
  }
  float4 f0 = *(const float4*)(src);
  float4 f1 = *(const float4*)(src + 4);
  __hip_bfloat16 tmp[8];
  tmp[0] = __float2bfloat16(f0.x); tmp[1] = __float2bfloat16(f0.y);
  tmp[2] = __float2bfloat16(f0.z); tmp[3] = __float2bfloat16(f0.w);
  tmp[4] = __float2bfloat16(f1.x); tmp[5] = __float2bfloat16(f1.y);
  tmp[6] = __float2bfloat16(f1.z); tmp[7] = __float2bfloat16(f1.w);
  *(uint4*)dst = *(const uint4*)tmp;
}

// Fused GEMM + LSTM gate epilogue.
// Block tile: 128 M-rows x (4 gates x 32 h-cols). 4 waves in 2(M) x 2(h16).
// Each wave: acc[im][gate] over 4 M-subtiles x 4 gates; the 4 gates of one
// (m,h) land in the SAME lane + reg -> epilogue is pure per-lane math.
__global__ __launch_bounds__(256, 2) void lstm_gemm_kernel(
    const __hip_bfloat16* __restrict__ A,   // [4096][2048]
    const __hip_bfloat16* __restrict__ W,   // [4096][2048] gate-major
    const float* __restrict__ bi, const float* __restrict__ bfv,
    const float* __restrict__ bc, const float* __restrict__ bo,
    const float* __restrict__ cprev,
    float* __restrict__ out)                // [h_next | c_next]
{
  __shared__ __align__(16) __hip_bfloat16 lA[BM * BK];  // 8 KB
  __shared__ __align__(16) __hip_bfloat16 lB[BM * BK];  // 8 KB (4g x 32h rows)

  const int m0 = blockIdx.x * BM;
  const int h0 = blockIdx.y * BN_H;
  const int tid = threadIdx.x;
  const int wave = tid >> 6;
  const int lane = tid & 63;
  const int wm = wave >> 1;   // which 64-row M half
  const int wn = wave & 1;    // which 16-col h half

  // Staging geometry: wave covers 16 rows/pass, lane -> (row, 16B chunk).
  // LDS dest must be wave-uniform-base + lane*16B -> unpadded [128][32] rows.
  const int srow = wave * 16 + (lane >> 2);   // 0..63
  const int scol = (lane & 3) * 8;            // bf16 element offset (16B chunk)

  floatx4 acc[4][4];
  #pragma unroll
  for (int i = 0; i < 4; ++i)
    #pragma unroll
    for (int j = 0; j < 4; ++j)
      acc[i][j] = (floatx4){0.f, 0.f, 0.f, 0.f};

  const __hip_bfloat16* aRow0 = A + (size_t)(m0 + srow) * D_K + scol;
  const __hip_bfloat16* aRow1 = A + (size_t)(m0 + 64 + srow) * D_K + scol;
  const int br0 = srow;        // B-tile rows 0..63   (gates 0..1)
  const int br1 = 64 + srow;   // B-tile rows 64..127 (gates 2..3)
  const __hip_bfloat16* bRow0 = W + (size_t)((br0 >> 5) * DH + h0 + (br0 & 31)) * D_K + scol;
  const __hip_bfloat16* bRow1 = W + (size_t)((br1 >> 5) * DH + h0 + (br1 & 31)) * D_K + scol;

  __hip_bfloat16* lA0 = &lA[srow * BK + scol];
  __hip_bfloat16* lA1 = &lA[(64 + srow) * BK + scol];
  __hip_bfloat16* lB0 = &lB[br0 * BK + scol];
  __hip_bfloat16* lB1 = &lB[br1 * BK + scol];

  for (int kt = 0; kt < D_K; kt += BK) {
    __builtin_amdgcn_global_load_lds(
        (const __attribute__((address_space(1))) void*)(aRow0 + kt),
        (__attribute__((address_space(3))) void*)lA0, 16, 0, 0);
    __builtin_amdgcn_global_load_lds(
        (const __attribute__((address_space(1))) void*)(aRow1 + kt),
        (__attribute__((address_space(3))) void*)lA1, 16, 0, 0);
    __builtin_amdgcn_global_load_lds(
        (const __attribute__((address_space(1))) void*)(bRow0 + kt),
        (__attribute__((address_space(3))) void*)lB0, 16, 0, 0);
    __builtin_amdgcn_global_load_lds(
        (const __attribute__((address_space(1))) void*)(bRow1 + kt),
        (__attribute__((address_space(3))) void*)lB1, 16, 0, 0);
    __syncthreads();

    short8 af[4], bfr[4];
    #pragma unroll
    for (int i = 0; i < 4; ++i) {
      int row = wm * 64 + i * 16 + (lane & 15);
      af[i] = *(const short8*)&lA[row * BK + (lane >> 4) * 8];
    }
    #pragma unroll
    for (int g = 0; g < 4; ++g) {
      int row = g * 32 + wn * 16 + (lane & 15);
      bfr[g] = *(const short8*)&lB[row * BK + (lane >> 4) * 8];
    }
    #pragma unroll
    for (int i = 0; i < 4; ++i)
      #pragma unroll
      for (int g = 0; g < 4; ++g)
        acc[i][g] = __builtin_amdgcn_mfma_f32_16x16x32_bf16(af[i], bfr[g], acc[i][g], 0, 0, 0);
    __syncthreads();
  }

  // Epilogue: C/D layout col=lane&15, row=(lane>>4)*4+reg.
  const int col = lane & 15;
  const int rq = lane >> 4;
  const int h = h0 + wn * 16 + col;
  const float bias_i = bi[h], bias_f = bfv[h], bias_c = bc[h], bias_o = bo[h];
  float* hout = out;
  float* cout = out + (size_t)B_SZ * DH;
  #pragma unroll
  for (int i = 0; i < 4; ++i) {
    int mb = m0 + wm * 64 + i * 16 + rq * 4;
    #pragma unroll
    for (int r = 0; r < 4; ++r) {
      int m = mb + r;
      float zi = acc[i][0][r] + bias_i;
      float zf = acc[i][1][r] + bias_f;
      float zc = acc[i][2][r] + bias_c;
      float zo = acc[i][3][r] + bias_o;
      float ig = fast_sigmoid(zi);
      float fg = fast_sigmoid(zf);
      float cg = fast_tanh(zc);
      float og = fast_sigmoid(zo);
      float cp = cprev[(size_t)m * DH + h];
      float cn = fg * cp + ig * cg;
      float hn = og * fast_tanh(cn);
      hout[(size_t)m * DH + h] = hn;
      cout[(size_t)m * DH + h] = cn;
    }
  }
}

extern "C" void kernel_launch(void* const* d_in, const int* in_sizes, int n_in,
                              void* d_out, int out_size, void* d_ws, size_t ws_size,
                              hipStream_t stream)
{
  const float* xin   = (const float*)d_in[0];
  const float* hprev = (const float*)d_in[1];
  const float* cprev = (const float*)d_in[2];
  const float* Wi    = (const float*)d_in[3];
  const float* bi    = (const float*)d_in[4];
  const float* Wf    = (const float*)d_in[5];
  const float* bfv   = (const float*)d_in[6];
  const float* Wc    = (const float*)d_in[7];
  const float* bc    = (const float*)d_in[8];
  const float* Wo    = (const float*)d_in[9];
  const float* bo    = (const float*)d_in[10];
  float* out = (float*)d_out;

  __hip_bfloat16* Abf = (__hip_bfloat16*)d_ws;                 // 16 MB
  __hip_bfloat16* Wbf = Abf + (size_t)B_SZ * D_K;              // 16 MB

  const int totalThreads = 2 * (B_SZ * D_K / 8);
  prep_kernel<<<totalThreads / 256, 256, 0, stream>>>(xin, hprev, Wi, Wf, Wc, Wo, Abf, Wbf);

  dim3 grid(B_SZ / BM, DH / BN_H);  // 32 x 32 = 1024 blocks
  lstm_gemm_kernel<<<grid, 256, 0, stream>>>(Abf, Wbf, bi, bfv, bc, bo, cprev, out);
}

// Round 2
// 216.127 us; speedup vs baseline: 1.0104x; 1.0104x over previous
//
#include <hip/hip_runtime.h>
#include <hip/hip_bf16.h>
#include <stdint.h>

#define B_SZ 4096
#define D_K  2048   // D_IN + D_H
#define DH   1024

#define BM 256      // M rows per block
#define BN_H 32     // h columns per block (x4 gates = 128 N columns)
#define BK 32       // K elements per LDS tile

typedef __attribute__((ext_vector_type(8))) short short8;
typedef __attribute__((ext_vector_type(4))) float floatx4;

__device__ __forceinline__ float fast_sigmoid(float x) {
  return 1.0f / (1.0f + __expf(-x));
}
__device__ __forceinline__ float fast_tanh(float x) {
  return 2.0f / (1.0f + __expf(-2.0f * x)) - 1.0f;
}

// Pack two fp32 -> bf16x2 (RNE) entirely in registers (no scratch array).
__device__ __forceinline__ uint32_t bf16pk(float a, float b) {
  union { float f; uint32_t u; } ua, ub;
  ua.f = a; ub.f = b;
  uint32_t x = ua.u + (0x7FFFu + ((ua.u >> 16) & 1u));
  uint32_t y = ub.u + (0x7FFFu + ((ub.u >> 16) & 1u));
  return (x >> 16) | (y & 0xFFFF0000u);
}

// Cast fp32 inputs to bf16 workspace:
//  Abf[m][k] = (k<1024 ? x[m][k] : h_prev[m][k-1024])          [4096][2048]
//  Wbf[g*1024+h][k] = W_g[h][k]   (gate-major concat)          [4096][2048]
__global__ __launch_bounds__(256) void prep_kernel(
    const float* __restrict__ xin, const float* __restrict__ hprev,
    const float* __restrict__ Wi, const float* __restrict__ Wf,
    const float* __restrict__ Wc, const float* __restrict__ Wo,
    uint32_t* __restrict__ Abf, uint32_t* __restrict__ Wbf)
{
  const int NT = (B_SZ * D_K) / 8;  // threads per matrix (8 elems/thread)
  int t = blockIdx.x * blockDim.x + threadIdx.x;
  const float* src;
  uint32_t* dst;
  if (t < NT) {
    int idx8 = t * 8;
    int m = idx8 >> 11;
    int k = idx8 & (D_K - 1);
    src = (k < 1024) ? (xin + m * 1024 + k) : (hprev + m * 1024 + (k - 1024));
    dst = Abf + t * 4;
  } else {
    int u = t - NT;
    int idx8 = u * 8;
    int n = idx8 >> 11;
    int k = idx8 & (D_K - 1);
    int g = n >> 10, h = n & 1023;
    const float* wsrc = (g == 0) ? Wi : (g == 1) ? Wf : (g == 2) ? Wc : Wo;
    src = wsrc + (size_t)h * D_K + k;
    dst = Wbf + u * 4;
  }
  float4 f0 = *(const float4*)(src);
  float4 f1 = *(const float4*)(src + 4);
  uint4 v;
  v.x = bf16pk(f0.x, f0.y);
  v.y = bf16pk(f0.z, f0.w);
  v.z = bf16pk(f1.x, f1.y);
  v.w = bf16pk(f1.z, f1.w);
  *(uint4*)dst = v;
}

// Fused GEMM + LSTM gate epilogue.
// Block tile: 256 M-rows x (4 gates x 32 h-cols). 4 waves: 2(M-half) x 2(h16).
// Wave tile: 128 M x 64 N as 8 M-frags x 4 gate-frags -> 12 LDS reads per
// 32 MFMAs (42.7 FLOP/LDS-byte).
// LDS bank swizzle: row r's logical 16B chunk c lives at physical chunk
// c ^ ((r>>1)&3). Staging realizes this by permuting the GLOBAL source chunk
// per lane (global_load_lds forces LDS dest = wavebase + lane*16).
__global__ __launch_bounds__(256, 2) void lstm_gemm_kernel(
    const __hip_bfloat16* __restrict__ A,   // [4096][2048]
    const __hip_bfloat16* __restrict__ W,   // [4096][2048] gate-major
    const float* __restrict__ bi, const float* __restrict__ bfv,
    const float* __restrict__ bc, const float* __restrict__ bo,
    const float* __restrict__ cprev,
    float* __restrict__ out)                // [h_next | c_next]
{
  __shared__ __align__(16) __hip_bfloat16 lA[BM * BK];   // 16 KB
  __shared__ __align__(16) __hip_bfloat16 lB[128 * BK];  // 8 KB (4g x 32h)

  const int m0 = blockIdx.x * BM;
  const int h0 = blockIdx.y * BN_H;
  const int tid = threadIdx.x;
  const int wave = tid >> 6;
  const int lane = tid & 63;
  const int wm = wave >> 1;   // which 128-row M half
  const int wn = wave & 1;    // which 16-col h half

  // ---- staging geometry (per global_load_lds: 4 lanes/row, 16 rows/wave)
  const int srow = (lane >> 2);               // row within 16-row strip
  const int gc   = (lane & 3) ^ ((lane >> 3) & 3);  // global chunk (swizzled)
  const int pc   = (lane & 3);                // physical LDS chunk (forced)

  // A: 4 strips of 64 rows; strip j covers rows j*64 + wave*16 + srow
  const __hip_bfloat16* aSrc[4];
  __hip_bfloat16* aDst[4];
  #pragma unroll
  for (int j = 0; j < 4; ++j) {
    int row = j * 64 + wave * 16 + srow;
    aSrc[j] = A + (size_t)(m0 + row) * D_K + gc * 8;
    aDst[j] = &lA[row * BK + pc * 8];
  }
  // B: 2 strips of 64 rows; B-tile row r -> W row (r>>5)*1024 + h0 + (r&31)
  const __hip_bfloat16* bSrc[2];
  __hip_bfloat16* bDst[2];
  #pragma unroll
  for (int j = 0; j < 2; ++j) {
    int row = j * 64 + wave * 16 + srow;
    bSrc[j] = W + (size_t)((row >> 5) * DH + h0 + (row & 31)) * D_K + gc * 8;
    bDst[j] = &lB[row * BK + pc * 8];
  }

  floatx4 acc[8][4];
  #pragma unroll
  for (int i = 0; i < 8; ++i)
    #pragma unroll
    for (int j = 0; j < 4; ++j)
      acc[i][j] = (floatx4){0.f, 0.f, 0.f, 0.f};

  // ---- fragment-read geometry
  const int fr = lane & 15;          // row within 16-row frag
  const int q  = lane >> 4;          // logical 16B chunk (k quarter)
  const int sw = (lane >> 1) & 3;    // swizzle key for rows ≡ fr (mod 16)
  const int rdOff = fr * BK + ((q ^ sw) * 8);   // element offset within frag row-block

  for (int kt = 0; kt < D_K; kt += BK) {
    #pragma unroll
    for (int j = 0; j < 4; ++j)
      __builtin_amdgcn_global_load_lds(
          (const __attribute__((address_space(1))) void*)(aSrc[j] + kt),
          (__attribute__((address_space(3))) void*)aDst[j], 16, 0, 0);
    #pragma unroll
    for (int j = 0; j < 2; ++j)
      __builtin_amdgcn_global_load_lds(
          (const __attribute__((address_space(1))) void*)(bSrc[j] + kt),
          (__attribute__((address_space(3))) void*)bDst[j], 16, 0, 0);
    __syncthreads();

    short8 bfr[4];
    #pragma unroll
    for (int g = 0; g < 4; ++g)
      bfr[g] = *(const short8*)&lB[(g * 32 + wn * 16) * BK + rdOff];
    #pragma unroll
    for (int i = 0; i < 8; ++i) {
      short8 af = *(const short8*)&lA[(wm * 128 + i * 16) * BK + rdOff];
      acc[i][0] = __builtin_amdgcn_mfma_f32_16x16x32_bf16(af, bfr[0], acc[i][0], 0, 0, 0);
      acc[i][1] = __builtin_amdgcn_mfma_f32_16x16x32_bf16(af, bfr[1], acc[i][1], 0, 0, 0);
      acc[i][2] = __builtin_amdgcn_mfma_f32_16x16x32_bf16(af, bfr[2], acc[i][2], 0, 0, 0);
      acc[i][3] = __builtin_amdgcn_mfma_f32_16x16x32_bf16(af, bfr[3], acc[i][3], 0, 0, 0);
    }
    __syncthreads();
  }

  // Epilogue: C/D layout col=lane&15, row=(lane>>4)*4+reg.
  const int col = lane & 15;
  const int rq = lane >> 4;
  const int h = h0 + wn * 16 + col;
  const float bias_i = bi[h], bias_f = bfv[h], bias_c = bc[h], bias_o = bo[h];
  float* hout = out;
  float* cout = out + (size_t)B_SZ * DH;
  #pragma unroll
  for (int i = 0; i < 8; ++i) {
    int mb = m0 + wm * 128 + i * 16 + rq * 4;
    #pragma unroll
    for (int r = 0; r < 4; ++r) {
      int m = mb + r;
      float zi = acc[i][0][r] + bias_i;
      float zf = acc[i][1][r] + bias_f;
      float zc = acc[i][2][r] + bias_c;
      float zo = acc[i][3][r] + bias_o;
      float ig = fast_sigmoid(zi);
      float fg = fast_sigmoid(zf);
      float cg = fast_tanh(zc);
      float og = fast_sigmoid(zo);
      float cp = cprev[(size_t)m * DH + h];
      float cn = fg * cp + ig * cg;
      float hn = og * fast_tanh(cn);
      hout[(size_t)m * DH + h] = hn;
      cout[(size_t)m * DH + h] = cn;
    }
  }
}

extern "C" void kernel_launch(void* const* d_in, const int* in_sizes, int n_in,
                              void* d_out, int out_size, void* d_ws, size_t ws_size,
                              hipStream_t stream)
{
  const float* xin   = (const float*)d_in[0];
  const float* hprev = (const float*)d_in[1];
  const float* cprev = (const float*)d_in[2];
  const float* Wi    = (const float*)d_in[3];
  const float* bi    = (const float*)d_in[4];
  const float* Wf    = (const float*)d_in[5];
  const float* bfv   = (const float*)d_in[6];
  const float* Wc    = (const float*)d_in[7];
  const float* bc    = (const float*)d_in[8];
  const float* Wo    = (const float*)d_in[9];
  const float* bo    = (const float*)d_in[10];
  float* out = (float*)d_out;

  __hip_bfloat16* Abf = (__hip_bfloat16*)d_ws;                 // 16 MB
  __hip_bfloat16* Wbf = Abf + (size_t)B_SZ * D_K;              // 16 MB

  const int totalThreads = 2 * (B_SZ * D_K / 8);
  prep_kernel<<<totalThreads / 256, 256, 0, stream>>>(
      xin, hprev, Wi, Wf, Wc, Wo, (uint32_t*)Abf, (uint32_t*)Wbf);

  dim3 grid(B_SZ / BM, DH / BN_H);  // 16 x 32 = 512 blocks
  lstm_gemm_kernel<<<grid, 256, 0, stream>>>(Abf, Wbf, bi, bfv, bc, bo, cprev, out);
}

// Round 3
// 208.411 us; speedup vs baseline: 1.0478x; 1.0370x over previous
//
#include <hip/hip_runtime.h>
#include <hip/hip_bf16.h>
#include <stdint.h>

#define B_SZ 4096
#define D_K  2048   // D_IN + D_H
#define DH   1024

#define BM 128      // M rows per block
#define BN_H 32     // h columns per block (x4 gates = 128 N columns)
#define BK 64       // K elements per LDS tile (2 MFMA k-steps)

typedef __attribute__((ext_vector_type(8))) short short8;
typedef __attribute__((ext_vector_type(4))) float floatx4;

__device__ __forceinline__ float fast_sigmoid(float x) {
  return 1.0f / (1.0f + __expf(-x));
}
__device__ __forceinline__ float fast_tanh(float x) {
  return 2.0f / (1.0f + __expf(-2.0f * x)) - 1.0f;
}

// Pack two fp32 -> bf16x2 (RNE) entirely in registers (no scratch array).
__device__ __forceinline__ uint32_t bf16pk(float a, float b) {
  union { float f; uint32_t u; } ua, ub;
  ua.f = a; ub.f = b;
  uint32_t x = ua.u + (0x7FFFu + ((ua.u >> 16) & 1u));
  uint32_t y = ub.u + (0x7FFFu + ((ub.u >> 16) & 1u));
  return (x >> 16) | (y & 0xFFFF0000u);
}

// Cast fp32 inputs to bf16 workspace:
//  Abf[m][k] = (k<1024 ? x[m][k] : h_prev[m][k-1024])          [4096][2048]
//  Wbf[g*1024+h][k] = W_g[h][k]   (gate-major concat)          [4096][2048]
__global__ __launch_bounds__(256) void prep_kernel(
    const float* __restrict__ xin, const float* __restrict__ hprev,
    const float* __restrict__ Wi, const float* __restrict__ Wf,
    const float* __restrict__ Wc, const float* __restrict__ Wo,
    uint32_t* __restrict__ Abf, uint32_t* __restrict__ Wbf)
{
  const int NT = (B_SZ * D_K) / 8;  // threads per matrix (8 elems/thread)
  int t = blockIdx.x * blockDim.x + threadIdx.x;
  const float* src;
  uint32_t* dst;
  if (t < NT) {
    int idx8 = t * 8;
    int m = idx8 >> 11;
    int k = idx8 & (D_K - 1);
    src = (k < 1024) ? (xin + m * 1024 + k) : (hprev + m * 1024 + (k - 1024));
    dst = Abf + t * 4;
  } else {
    int u = t - NT;
    int idx8 = u * 8;
    int n = idx8 >> 11;
    int k = idx8 & (D_K - 1);
    int g = n >> 10, h = n & 1023;
    const float* wsrc = (g == 0) ? Wi : (g == 1) ? Wf : (g == 2) ? Wc : Wo;
    src = wsrc + (size_t)h * D_K + k;
    dst = Wbf + u * 4;
  }
  float4 f0 = *(const float4*)(src);
  float4 f1 = *(const float4*)(src + 4);
  uint4 v;
  v.x = bf16pk(f0.x, f0.y);
  v.y = bf16pk(f0.z, f0.w);
  v.z = bf16pk(f1.x, f1.y);
  v.w = bf16pk(f1.z, f1.w);
  *(uint4*)dst = v;
}

// Fused GEMM + LSTM gate epilogue.
// Block tile: 128 M x (4 gates x 32 h). 4 waves: 2(M64) x 2(h16).
// Wave tile 64x64 = 4 M-frags x 4 gate-frags; 4 gates of one (m,h) land in
// the same lane+reg -> pure per-lane epilogue.
// BK=64: 32 K-iters (half the barriers), 8 global_load_lds in flight/wave.
// Swizzle: row r (128B wide, 8 x 16B chunks) stores logical chunk c at
// physical chunk c ^ (r & 7) -> all LDS read/write phases are 2-way (free).
// global_load_lds forces LDS dst = wavebase + lane*16, so the swizzle is
// realized by permuting the global SOURCE chunk per lane.
__global__ __launch_bounds__(256, 3) void lstm_gemm_kernel(
    const __hip_bfloat16* __restrict__ A,   // [4096][2048]
    const __hip_bfloat16* __restrict__ W,   // [4096][2048] gate-major
    const float* __restrict__ bi, const float* __restrict__ bfv,
    const float* __restrict__ bc, const float* __restrict__ bo,
    const float* __restrict__ cprev,
    float* __restrict__ out)                // [h_next | c_next]
{
  __shared__ __align__(16) __hip_bfloat16 lA[BM * BK];   // 16 KB
  __shared__ __align__(16) __hip_bfloat16 lB[128 * BK];  // 16 KB

  const int m0 = blockIdx.x * BM;
  const int h0 = blockIdx.y * BN_H;
  const int tid = threadIdx.x;
  const int wave = tid >> 6;
  const int lane = tid & 63;
  const int wm = wave >> 1;   // M half (64 rows)
  const int wn = wave & 1;    // h half (16 cols)

  // ---- staging geometry: one load = 64 lanes x 16B = 8 rows of 128B.
  const int sr = lane >> 3;          // row within 8-row group (0..7)
  const int pc = lane & 7;           // physical chunk (forced by HW)
  const int gc = pc ^ sr;            // global source chunk (swizzle key = row&7 = sr)

  // A: 4 strips; strip j covers rows j*32 + wave*8 + sr
  const __hip_bfloat16* aSrc[4];
  const __hip_bfloat16* bSrc[4];
  __hip_bfloat16* aDst[4];
  __hip_bfloat16* bDst[4];
  #pragma unroll
  for (int j = 0; j < 4; ++j) {
    int row = j * 32 + wave * 8 + sr;
    aSrc[j] = A + (size_t)(m0 + row) * D_K + gc * 8;
    aDst[j] = &lA[row * BK + pc * 8];
    // B tile row r: gate = r>>5 = j, h = h0 + (r&31)
    bSrc[j] = W + (size_t)(j * DH + h0 + wave * 8 + sr) * D_K + gc * 8;
    bDst[j] = &lB[row * BK + pc * 8];
  }

  floatx4 acc[4][4];
  #pragma unroll
  for (int i = 0; i < 4; ++i)
    #pragma unroll
    for (int j = 0; j < 4; ++j)
      acc[i][j] = (floatx4){0.f, 0.f, 0.f, 0.f};

  // ---- fragment-read geometry
  const int fr = lane & 15;          // row within 16-row frag
  const int q  = lane >> 4;          // k quarter (16B) within 64B k-half
  const int key = fr & 7;            // swizzle key (row & 7)
  // element offset of logical chunk (kk*4+q) in swizzled row:
  const int cx0 = ((q + 0) ^ key) * 8;   // kk = 0
  const int cx1 = ((q + 4) ^ key) * 8;   // kk = 1

  for (int kt = 0; kt < D_K; kt += BK) {
    #pragma unroll
    for (int j = 0; j < 4; ++j)
      __builtin_amdgcn_global_load_lds(
          (const __attribute__((address_space(1))) void*)(aSrc[j] + kt),
          (__attribute__((address_space(3))) void*)aDst[j], 16, 0, 0);
    #pragma unroll
    for (int j = 0; j < 4; ++j)
      __builtin_amdgcn_global_load_lds(
          (const __attribute__((address_space(1))) void*)(bSrc[j] + kt),
          (__attribute__((address_space(3))) void*)bDst[j], 16, 0, 0);
    __syncthreads();

    #pragma unroll
    for (int kk = 0; kk < 2; ++kk) {
      const int cx = kk ? cx1 : cx0;
      short8 bfr[4];
      #pragma unroll
      for (int g = 0; g < 4; ++g)
        bfr[g] = *(const short8*)&lB[(g * 32 + wn * 16 + fr) * BK + cx];
      #pragma unroll
      for (int i = 0; i < 4; ++i) {
        short8 af = *(const short8*)&lA[(wm * 64 + i * 16 + fr) * BK + cx];
        acc[i][0] = __builtin_amdgcn_mfma_f32_16x16x32_bf16(af, bfr[0], acc[i][0], 0, 0, 0);
        acc[i][1] = __builtin_amdgcn_mfma_f32_16x16x32_bf16(af, bfr[1], acc[i][1], 0, 0, 0);
        acc[i][2] = __builtin_amdgcn_mfma_f32_16x16x32_bf16(af, bfr[2], acc[i][2], 0, 0, 0);
        acc[i][3] = __builtin_amdgcn_mfma_f32_16x16x32_bf16(af, bfr[3], acc[i][3], 0, 0, 0);
      }
    }
    __syncthreads();
  }

  // Epilogue: C/D layout col=lane&15, row=(lane>>4)*4+reg.
  const int col = lane & 15;
  const int rq = lane >> 4;
  const int h = h0 + wn * 16 + col;
  const float bias_i = bi[h], bias_f = bfv[h], bias_c = bc[h], bias_o = bo[h];
  float* hout = out;
  float* cout = out + (size_t)B_SZ * DH;
  #pragma unroll
  for (int i = 0; i < 4; ++i) {
    int mb = m0 + wm * 64 + i * 16 + rq * 4;
    #pragma unroll
    for (int r = 0; r < 4; ++r) {
      int m = mb + r;
      float zi = acc[i][0][r] + bias_i;
      float zf = acc[i][1][r] + bias_f;
      float zc = acc[i][2][r] + bias_c;
      float zo = acc[i][3][r] + bias_o;
      float ig = fast_sigmoid(zi);
      float fg = fast_sigmoid(zf);
      float cg = fast_tanh(zc);
      float og = fast_sigmoid(zo);
      float cp = cprev[(size_t)m * DH + h];
      float cn = fg * cp + ig * cg;
      float hn = og * fast_tanh(cn);
      hout[(size_t)m * DH + h] = hn;
      cout[(size_t)m * DH + h] = cn;
    }
  }
}

extern "C" void kernel_launch(void* const* d_in, const int* in_sizes, int n_in,
                              void* d_out, int out_size, void* d_ws, size_t ws_size,
                              hipStream_t stream)
{
  const float* xin   = (const float*)d_in[0];
  const float* hprev = (const float*)d_in[1];
  const float* cprev = (const float*)d_in[2];
  const float* Wi    = (const float*)d_in[3];
  const float* bi    = (const float*)d_in[4];
  const float* Wf    = (const float*)d_in[5];
  const float* bfv   = (const float*)d_in[6];
  const float* Wc    = (const float*)d_in[7];
  const float* bc    = (const float*)d_in[8];
  const float* Wo    = (const float*)d_in[9];
  const float* bo    = (const float*)d_in[10];
  float* out = (float*)d_out;

  __hip_bfloat16* Abf = (__hip_bfloat16*)d_ws;                 // 16 MB
  __hip_bfloat16* Wbf = Abf + (size_t)B_SZ * D_K;              // 16 MB

  const int totalThreads = 2 * (B_SZ * D_K / 8);
  prep_kernel<<<totalThreads / 256, 256, 0, stream>>>(
      xin, hprev, Wi, Wf, Wc, Wo, (uint32_t*)Abf, (uint32_t*)Wbf);

  dim3 grid(B_SZ / BM, DH / BN_H);  // 32 x 32 = 1024 blocks
  lstm_gemm_kernel<<<grid, 256, 0, stream>>>(Abf, Wbf, bi, bfv, bc, bo, cprev, out);
}